// Round 4
// baseline (258.791 us; speedup 1.0000x reference)
//
#include <hip/hip_runtime.h>
#include <hip/hip_bf16.h>

namespace {

constexpr int NU = 8000;
constexpr int NI = 4000;
constexpr int NN = 12000;          // total nodes
constexpr int D  = 64;             // embedding dim
constexpr int NE = 300000;         // input (undirected) edges

// ---------------- kernels ----------------

// Detect edge_index storage width. Values < 12000 < 2^16, so for int64
// (little-endian) every odd 32-bit word is 0. Any nonzero odd word => int32.
__global__ void detect_edge_dtype(const unsigned int* __restrict__ raw, int* __restrict__ flag) {
    unsigned int v = raw[2 * threadIdx.x + 1];
    if (v != 0) atomicOr(flag, 1);
}

// Detect embedding storage: bf16 vs fp32. Legit bf16 embeddings satisfy
// |v| < 0.04 (exponent field <= 122). If storage is fp32, even-index uint16s
// are float mantissa low-halves with ~uniform exponent fields; any sampled
// exponent > 126 (|v| >= 0.5) marks fp32 (flag=1).
__global__ void detect_emb_dtype(const unsigned short* __restrict__ raw, int* __restrict__ flag) {
    unsigned short u = raw[2 * threadIdx.x];          // even indices 0..510
    int e = (u >> 7) & 0xFF;
    if (e > 126) atomicOr(flag, 1);
}

__device__ __forceinline__ void load_edge(const unsigned int* __restrict__ raw, int is32,
                                          int t, int& a, int& b) {
    if (is32) { a = (int)raw[t];         b = (int)raw[NE + t]; }
    else      { a = (int)raw[2 * t];     b = (int)raw[2 * NE + 2 * t]; }
}

// Pass 1: duplicate-tolerant degree count (each edge contributes (a,b) and (b,a);
// self-loop contributes a single (a,a)).
__global__ void count_deg(const unsigned int* __restrict__ raw, const int* __restrict__ flag,
                          int* __restrict__ degd) {
    int t = blockIdx.x * blockDim.x + threadIdx.x;
    if (t >= NE) return;
    int a, b; load_edge(raw, *flag, t, a, b);
    atomicAdd(&degd[a], 1);
    if (b != a) atomicAdd(&degd[b], 1);
}

// exclusive prefix sum over degd[NN] -> rp[NN+1], single 1024-thread block
__global__ void scan_rows(const int* __restrict__ degd, int* __restrict__ rp) {
    __shared__ int sums[1024];
    int t = threadIdx.x;
    constexpr int CH = (NN + 1023) / 1024;   // 12
    int start = t * CH;
    int end   = start + CH < NN ? start + CH : NN;
    int s = 0;
    for (int i = start; i < end; ++i) s += degd[i];
    sums[t] = s;
    __syncthreads();
    for (int off = 1; off < 1024; off <<= 1) {   // Hillis-Steele inclusive scan
        int v = (t >= off) ? sums[t - off] : 0;
        __syncthreads();
        sums[t] += v;
        __syncthreads();
    }
    int excl = (t == 0) ? 0 : sums[t - 1];
    for (int i = start; i < end; ++i) { rp[i] = excl; excl += degd[i]; }
    if (t == 1023) rp[NN] = sums[1023];
}

// Pass 2: scatter directed entries (with duplicates) into per-row segments.
__global__ void scatter_edges(const unsigned int* __restrict__ raw, const int* __restrict__ flag,
                              const int* __restrict__ rp, int* __restrict__ fill,
                              int* __restrict__ col) {
    int t = blockIdx.x * blockDim.x + threadIdx.x;
    if (t >= NE) return;
    int a, b; load_edge(raw, *flag, t, a, b);
    col[rp[a] + atomicAdd(&fill[a], 1)] = b;
    if (b != a) col[rp[b] + atomicAdd(&fill[b], 1)] = a;
}

// Pass 3: per-row dedup via per-wave LDS bitset (12000 bits = 375 words).
// One wave per row; winners compact in place. Safe: a chunk's stores go to
// positions < next chunk's read indices, and within a chunk the store is
// data-dependent on the load (wave-level in-order: loads drain before stores).
__global__ __launch_bounds__(256) void dedup_rows(const int* __restrict__ rp,
                                                  const int* __restrict__ degd,
                                                  int* __restrict__ col,
                                                  int* __restrict__ degu) {
    __shared__ unsigned int bits[4][376];
    __shared__ int wcnt[4];
    int wave = threadIdx.x >> 6, lane = threadIdx.x & 63;
    int row = blockIdx.x * 4 + wave;
    if (row >= NN) return;
    unsigned int* bb = bits[wave];
    for (int wrd = lane; wrd < 376; wrd += 64) bb[wrd] = 0;
    if (lane == 0) wcnt[wave] = 0;
    int s = rp[row], n = degd[row];
    for (int base = 0; base < n; base += 64) {
        int idx = base + lane;
        int c = -1;
        if (idx < n) c = col[s + idx];
        if (c >= 0) {
            unsigned int old = atomicOr(&bb[c >> 5], 1u << (c & 31));
            if (!((old >> (c & 31)) & 1u)) {
                int p = atomicAdd(&wcnt[wave], 1);
                col[s + p] = c;        // in-place compaction, order irrelevant
            }
        }
    }
    if (lane == 0) degu[row] = wcnt[wave];
}

// dinv[i] = 1/sqrt(max(deg_unique, 1))
__global__ void make_dinv(const int* __restrict__ degu, float* __restrict__ dinv) {
    int i = blockIdx.x * blockDim.x + threadIdx.x;
    if (i >= NN) return;
    int d = degu[i];
    dinv[i] = rsqrtf((float)(d > 0 ? d : 1));
}

// X0 = concat(user_emb, item_emb) as fp32; acc = X0. Handles bf16 or fp32
// embedding storage per detected flag.
__global__ void init_x(const void* __restrict__ uev, const void* __restrict__ iev,
                       const int* __restrict__ emb_is_fp32,
                       float* __restrict__ x0, float* __restrict__ acc) {
    int i = blockIdx.x * blockDim.x + threadIdx.x;
    if (i >= NN * D) return;
    float v;
    if (*emb_is_fp32) {
        v = (i < NU * D) ? ((const float*)uev)[i] : ((const float*)iev)[i - NU * D];
    } else {
        v = (i < NU * D) ? __bfloat162float(((const __hip_bfloat16*)uev)[i])
                         : __bfloat162float(((const __hip_bfloat16*)iev)[i - NU * D]);
    }
    x0[i]  = v;
    acc[i] = v;
}

// y = A_hat * x ; acc += y. One wave (64 lanes = 64 dims) per row.
// weight(r,c) = dinv[r]*dinv[c] computed inline (dinv is L2-resident, 48 KB).
__global__ __launch_bounds__(256) void spmm(const int* __restrict__ rp,
                                            const int* __restrict__ degu,
                                            const int* __restrict__ col,
                                            const float* __restrict__ dinv,
                                            const float* __restrict__ x,
                                            float* __restrict__ y,
                                            float* __restrict__ acc) {
    int gid  = blockIdx.x * blockDim.x + threadIdx.x;
    int row  = gid >> 6;
    int lane = gid & 63;
    if (row >= NN) return;
    int s = rp[row], n = degu[row];
    float dr  = dinv[row];
    float sum = 0.f;
    int k = 0;
    for (; k + 1 < n; k += 2) {
        int   c0 = col[s + k], c1 = col[s + k + 1];
        float w0 = dinv[c0] * dr, w1 = dinv[c1] * dr;
        float v0 = x[c0 * D + lane];
        float v1 = x[c1 * D + lane];
        sum = fmaf(w0, v0, sum);
        sum = fmaf(w1, v1, sum);
    }
    if (k < n) {
        int c0 = col[s + k];
        sum = fmaf(dinv[c0] * dr, x[c0 * D + lane], sum);
    }
    y[row * D + lane]    = sum;
    acc[row * D + lane] += sum;
}

// out = fp32(acc / 4) — reference output dtype is float32.
__global__ void finalize(const float* __restrict__ acc, float* __restrict__ out) {
    int i = blockIdx.x * blockDim.x + threadIdx.x;
    if (i >= NN * D) return;
    out[i] = acc[i] * 0.25f;
}

} // namespace

extern "C" void kernel_launch(void* const* d_in, const int* in_sizes, int n_in,
                              void* d_out, int out_size, void* d_ws, size_t ws_size,
                              hipStream_t stream) {
    // Identify inputs by element count (robust to ordering).
    int ei = 0, ui = 1, ii = 2;
    for (int i = 0; i < n_in; ++i) {
        if      (in_sizes[i] == 2 * NE) ei = i;
        else if (in_sizes[i] == NU * D) ui = i;
        else if (in_sizes[i] == NI * D) ii = i;
    }
    const unsigned int* raw = (const unsigned int*)d_in[ei];
    const void*         uev = d_in[ui];
    const void*         iev = d_in[ii];
    float*              out = (float*)d_out;

    // ---- workspace layout (~11.9 MB total) ----
    char* ws = (char*)d_ws;
    size_t off = 0;
    auto take = [&](size_t bytes) {
        void* p = ws + off;
        off += (bytes + 15) & ~(size_t)15;
        return p;
    };
    int*   degd  = (int*)take(NN * 4);
    int*   fill  = (int*)take(NN * 4);
    int*   eflag = (int*)take(16);
    int*   fflag = (int*)take(16);
    size_t zero_bytes = off;                 // degd+fill+eflag+fflag contiguous
    int*   rp   = (int*)take((NN + 1) * 4);
    int*   degu = (int*)take(NN * 4);
    float* dinv = (float*)take(NN * 4);
    int*   col  = (int*)take((size_t)(2 * NE) * 4);     // 2.4 MB
    float* x0   = (float*)take((size_t)NN * D * 4);     // 3 MB
    float* x1   = (float*)take((size_t)NN * D * 4);     // 3 MB
    float* acc  = (float*)take((size_t)NN * D * 4);     // 3 MB
    (void)ws_size;

    hipMemsetAsync(degd, 0, zero_bytes, stream);

    detect_edge_dtype<<<1, 256, 0, stream>>>(raw, eflag);
    detect_emb_dtype <<<1, 256, 0, stream>>>((const unsigned short*)uev, fflag);
    count_deg        <<<(NE + 255) / 256, 256, 0, stream>>>(raw, eflag, degd);
    scan_rows        <<<1, 1024, 0, stream>>>(degd, rp);
    scatter_edges    <<<(NE + 255) / 256, 256, 0, stream>>>(raw, eflag, rp, fill, col);
    dedup_rows       <<<(NN + 3) / 4, 256, 0, stream>>>(rp, degd, col, degu);
    make_dinv        <<<(NN + 255) / 256, 256, 0, stream>>>(degu, dinv);
    init_x           <<<(NN * D + 255) / 256, 256, 0, stream>>>(uev, iev, fflag, x0, acc);

    // 3 propagation layers, ping-pong x0/x1, accumulate into acc
    int spmm_blocks = (NN * 64 + 255) / 256;   // one wave per row
    spmm<<<spmm_blocks, 256, 0, stream>>>(rp, degu, col, dinv, x0, x1, acc);
    spmm<<<spmm_blocks, 256, 0, stream>>>(rp, degu, col, dinv, x1, x0, acc);
    spmm<<<spmm_blocks, 256, 0, stream>>>(rp, degu, col, dinv, x0, x1, acc);

    finalize<<<(NN * D + 255) / 256, 256, 0, stream>>>(acc, out);
}